// Round 1
// baseline (326.408 us; speedup 1.0000x reference)
//
#include <hip/hip_runtime.h>
#include <hip/hip_bf16.h>

using bf16 = __hip_bfloat16;

typedef __attribute__((ext_vector_type(8))) __bf16 bf16x8;
typedef __attribute__((ext_vector_type(4))) float floatx4;

#define EPS 1e-6f

// ---------------------------------------------------------------------------
// async global->LDS, 16B per lane
// ---------------------------------------------------------------------------
__device__ __forceinline__ void load_lds16(const void* g, void* l) {
    __builtin_amdgcn_global_load_lds(
        (const __attribute__((address_space(1))) void*)g,
        (__attribute__((address_space(3))) void*)l, 16, 0, 0);
}

__device__ __forceinline__ void storeOut(float* p, float v) { *p = v; }
__device__ __forceinline__ void storeOut(bf16* p, float v) { *p = __float2bfloat16(v); }

// ---------------------------------------------------------------------------
// Canonical NT GEMM: D[m][n] = sum_k A[m][k] * B[n][k]
// A: (M x K) row-major bf16, B: (N x K) row-major bf16.
// BM=BN=128, BK=32. 256 threads = 4 waves in 2x2, each wave 64x64 (4x4 MFMA).
// BIAS_MODE: 0 none, 1 along m, 2 along n. SCALE_EN: multiply by scale.
// RESID_EN: add resid[z][m][n] (fp32).
// ---------------------------------------------------------------------------
template <int BIAS_MODE, int SCALE_EN, int RESID_EN, typename OutT>
__global__ __launch_bounds__(256) void gemm_nt(
    const bf16* __restrict__ A, long long aStride,
    const bf16* __restrict__ B, long long bStride,
    OutT* __restrict__ D, long long dStride,
    const float* __restrict__ bias,
    const float* __restrict__ resid, long long rStride,
    int N, int K, float scale)
{
    __shared__ bf16 As[128 * 32];
    __shared__ bf16 Bs[128 * 32];

    const int tid  = threadIdx.x;
    const int lane = tid & 63;
    const int wave = tid >> 6;
    const int wm   = wave >> 1;      // 0..1
    const int wn   = wave & 1;       // 0..1
    const int m0   = blockIdx.y * 128;
    const int n0   = blockIdx.x * 128;
    const int z    = blockIdx.z;

    const bf16* Ab = A + (size_t)z * aStride + (size_t)m0 * K;
    const bf16* Bb = B + (size_t)z * bStride + (size_t)n0 * K;

    floatx4 acc[4][4];
#pragma unroll
    for (int i = 0; i < 4; ++i)
#pragma unroll
        for (int j = 0; j < 4; ++j) acc[i][j] = (floatx4){0.f, 0.f, 0.f, 0.f};

    // LDS layout: flat 16B slot idx = kq*128 + row  (kq = k-chunk of 8 bf16)
    // fragment byte base for this lane:
    const int fragBase = ((lane >> 4) * 128 + (lane & 15)) * 16;
    const char* AsB = (const char*)As;
    const char* BsB = (const char*)Bs;

    const int i1 = tid, i2 = tid + 256;
    const int r1 = i1 & 127, q1 = i1 >> 7;
    const int r2 = i2 & 127, q2 = i2 >> 7;

    const int kIters = K >> 5;
    for (int kt = 0; kt < kIters; ++kt) {
        const int k0 = kt << 5;
        load_lds16(Ab + (size_t)r1 * K + k0 + q1 * 8, (char*)As + i1 * 16);
        load_lds16(Ab + (size_t)r2 * K + k0 + q2 * 8, (char*)As + i2 * 16);
        load_lds16(Bb + (size_t)r1 * K + k0 + q1 * 8, (char*)Bs + i1 * 16);
        load_lds16(Bb + (size_t)r2 * K + k0 + q2 * 8, (char*)Bs + i2 * 16);
        __syncthreads();

        bf16x8 af[4], bfr[4];
#pragma unroll
        for (int im = 0; im < 4; ++im) {
            const int tm = wm * 64 + im * 16;
            af[im] = *(const bf16x8*)(AsB + fragBase + tm * 16);
        }
#pragma unroll
        for (int in = 0; in < 4; ++in) {
            const int tn = wn * 64 + in * 16;
            bfr[in] = *(const bf16x8*)(BsB + fragBase + tn * 16);
        }
#pragma unroll
        for (int im = 0; im < 4; ++im)
#pragma unroll
            for (int in = 0; in < 4; ++in)
                acc[im][in] = __builtin_amdgcn_mfma_f32_16x16x32_bf16(
                    af[im], bfr[in], acc[im][in], 0, 0, 0);
        __syncthreads();
    }

    // Epilogue. D layout: col = lane&15, row = (lane>>4)*4 + reg
    const size_t dbase = (size_t)z * dStride;
#pragma unroll
    for (int im = 0; im < 4; ++im) {
        const int gmb = m0 + wm * 64 + im * 16 + ((lane >> 4) << 2);
#pragma unroll
        for (int in = 0; in < 4; ++in) {
            const int gn = n0 + wn * 64 + in * 16 + (lane & 15);
            float bn = 0.f;
            if (BIAS_MODE == 2) bn = bias[gn];
#pragma unroll
            for (int r = 0; r < 4; ++r) {
                const int gm = gmb + r;
                float v = acc[im][in][r];
                if (SCALE_EN) v *= scale;
                if (BIAS_MODE == 1) v += bias[gm];
                if (BIAS_MODE == 2) v += bn;
                if (RESID_EN) v += resid[(size_t)z * rStride + (size_t)gm * N + gn];
                storeOut(D + dbase + (size_t)gm * N + gn, v);
            }
        }
    }
}

// ---------------------------------------------------------------------------
// GroupNorm stats: one block per (b, g); 16 ch x 1024 = 16384 contiguous floats
// ---------------------------------------------------------------------------
__global__ __launch_bounds__(256) void gn_stats(const float* __restrict__ x,
                                                float* __restrict__ stats)
{
    const int bg = blockIdx.x;
    const float4* p = (const float4*)(x + (size_t)bg * 16384);
    float s = 0.f, ss = 0.f;
    for (int i = threadIdx.x; i < 4096; i += 256) {
        float4 v = p[i];
        s  += v.x + v.y + v.z + v.w;
        ss += v.x * v.x + v.y * v.y + v.z * v.z + v.w * v.w;
    }
#pragma unroll
    for (int off = 32; off; off >>= 1) {
        s  += __shfl_down(s, off);
        ss += __shfl_down(ss, off);
    }
    __shared__ float rs[4], rss[4];
    const int wv = threadIdx.x >> 6;
    if ((threadIdx.x & 63) == 0) { rs[wv] = s; rss[wv] = ss; }
    __syncthreads();
    if (threadIdx.x == 0) {
        float S  = rs[0] + rs[1] + rs[2] + rs[3];
        float SS = rss[0] + rss[1] + rss[2] + rss[3];
        float mean = S * (1.f / 16384.f);
        float var  = SS * (1.f / 16384.f) - mean * mean;
        stats[2 * bg]     = mean;
        stats[2 * bg + 1] = rsqrtf(var + EPS);
    }
}

// ---------------------------------------------------------------------------
// GN apply + transpose: x (B,512,1024) fp32 -> xnT (B,1024,512) bf16
// grid (HW/32, C/32, B), 256 threads, 32x32 LDS tile
// ---------------------------------------------------------------------------
__global__ __launch_bounds__(256) void gn_apply_t(const float* __restrict__ x,
                                                  const float* __restrict__ stats,
                                                  const float* __restrict__ gamma,
                                                  const float* __restrict__ beta,
                                                  bf16* __restrict__ xnT)
{
    __shared__ bf16 tile[32][36];
    const int b = blockIdx.z, c0 = blockIdx.y * 32, i0 = blockIdx.x * 32;
    {
        const int cc = threadIdx.x >> 3;
        const int i4 = (threadIdx.x & 7) << 2;
        const int c  = c0 + cc;
        const float mean = stats[2 * ((b << 5) + (c >> 4))];
        const float rstd = stats[2 * ((b << 5) + (c >> 4)) + 1];
        const float a  = gamma[c] * rstd;
        const float bb = beta[c] - mean * a;
        float4 v = *(const float4*)(x + (((size_t)(b * 512 + c)) << 10) + i0 + i4);
        tile[cc][i4 + 0] = __float2bfloat16(v.x * a + bb);
        tile[cc][i4 + 1] = __float2bfloat16(v.y * a + bb);
        tile[cc][i4 + 2] = __float2bfloat16(v.z * a + bb);
        tile[cc][i4 + 3] = __float2bfloat16(v.w * a + bb);
    }
    __syncthreads();
    {
        const int ii = threadIdx.x >> 3;
        const int c4 = (threadIdx.x & 7) << 2;
        union { bf16 h[4]; uint2 u; } pk;
        pk.h[0] = tile[c4 + 0][ii];
        pk.h[1] = tile[c4 + 1][ii];
        pk.h[2] = tile[c4 + 2][ii];
        pk.h[3] = tile[c4 + 3][ii];
        *((uint2*)(xnT + (((size_t)(b * 1024 + i0 + ii)) << 9) + c0 + c4)) = pk.u;
    }
}

// ---------------------------------------------------------------------------
// Row softmax: E (rows,1024) fp32 -> P (rows,1024) bf16. One block per row.
// ---------------------------------------------------------------------------
__global__ __launch_bounds__(256) void softmax_row(const float* __restrict__ E,
                                                   bf16* __restrict__ P)
{
    const float* e = E + (size_t)blockIdx.x * 1024;
    bf16* p = P + (size_t)blockIdx.x * 1024;
    float4 v = ((const float4*)e)[threadIdx.x];
    float mx = fmaxf(fmaxf(v.x, v.y), fmaxf(v.z, v.w));
#pragma unroll
    for (int off = 32; off; off >>= 1) mx = fmaxf(mx, __shfl_xor(mx, off));
    __shared__ float sm[4], ssum[4];
    if ((threadIdx.x & 63) == 0) sm[threadIdx.x >> 6] = mx;
    __syncthreads();
    mx = fmaxf(fmaxf(sm[0], sm[1]), fmaxf(sm[2], sm[3]));
    float e0 = __expf(v.x - mx), e1 = __expf(v.y - mx);
    float e2 = __expf(v.z - mx), e3 = __expf(v.w - mx);
    float s = e0 + e1 + e2 + e3;
#pragma unroll
    for (int off = 32; off; off >>= 1) s += __shfl_xor(s, off);
    if ((threadIdx.x & 63) == 0) ssum[threadIdx.x >> 6] = s;
    __syncthreads();
    s = ssum[0] + ssum[1] + ssum[2] + ssum[3];
    const float inv = 1.f / s;
    union { bf16 h[4]; uint2 u; } pk;
    pk.h[0] = __float2bfloat16(e0 * inv);
    pk.h[1] = __float2bfloat16(e1 * inv);
    pk.h[2] = __float2bfloat16(e2 * inv);
    pk.h[3] = __float2bfloat16(e3 * inv);
    ((uint2*)p)[threadIdx.x] = pk.u;
}

// ---------------------------------------------------------------------------
// fp32 -> bf16 weight convert (n4 = n/4 float4 groups)
// ---------------------------------------------------------------------------
__global__ __launch_bounds__(256) void cvt_bf16(const float* __restrict__ s,
                                                bf16* __restrict__ d, int n4)
{
    const int i = blockIdx.x * 256 + threadIdx.x;
    if (i < n4) {
        float4 v = ((const float4*)s)[i];
        union { bf16 h[4]; uint2 u; } pk;
        pk.h[0] = __float2bfloat16(v.x);
        pk.h[1] = __float2bfloat16(v.y);
        pk.h[2] = __float2bfloat16(v.z);
        pk.h[3] = __float2bfloat16(v.w);
        ((uint2*)d)[i] = pk.u;
    }
}

// ---------------------------------------------------------------------------
extern "C" void kernel_launch(void* const* d_in, const int* in_sizes, int n_in,
                              void* d_out, int out_size, void* d_ws, size_t ws_size,
                              hipStream_t stream)
{
    const float* x     = (const float*)d_in[0];
    const float* gamma = (const float*)d_in[1];
    const float* beta  = (const float*)d_in[2];
    const float* wq    = (const float*)d_in[3];
    const float* bq    = (const float*)d_in[4];
    const float* wk    = (const float*)d_in[5];
    const float* bk    = (const float*)d_in[6];
    const float* wv    = (const float*)d_in[7];
    const float* bv    = (const float*)d_in[8];
    const float* wp    = (const float*)d_in[9];
    const float* bp    = (const float*)d_in[10];
    float* out = (float*)d_out;

    char* ws = (char*)d_ws;
    size_t off = 0;
    auto alloc = [&](size_t bytes) -> char* {
        char* p = ws + off;
        off += (bytes + 255) & ~(size_t)255;
        return p;
    };

    const long long S  = 1024, C = 512;
    const long long BS = S * C;           // 524288 elements per batch (x/q/k/v/...)
    const long long ES = S * S;           // 1048576 per batch (energy/attn)

    float* stats = (float*)alloc(512 * 2 * sizeof(float));
    bf16* wqb = (bf16*)alloc((size_t)C * C * 2);
    bf16* wkb = (bf16*)alloc((size_t)C * C * 2);
    bf16* wvb = (bf16*)alloc((size_t)C * C * 2);
    bf16* wpb = (bf16*)alloc((size_t)C * C * 2);
    bf16* xnT = (bf16*)alloc((size_t)16 * BS * 2);
    bf16* qT  = (bf16*)alloc((size_t)16 * BS * 2);
    bf16* kT  = (bf16*)alloc((size_t)16 * BS * 2);
    bf16* vv  = (bf16*)alloc((size_t)16 * BS * 2);
    bf16* O2  = (bf16*)alloc((size_t)16 * BS * 2);

    // chunk E (fp32) + P (bf16) by batch groups to fit ws
    int CB = 16;
    while (CB > 1 && off + (size_t)CB * (ES * 4 + ES * 2) + 1024 > ws_size) CB >>= 1;
    float* E = (float*)alloc((size_t)CB * ES * 4);
    bf16*  P = (bf16*)alloc((size_t)CB * ES * 2);

    // weights fp32 -> bf16
    cvt_bf16<<<256, 256, 0, stream>>>(wq, wqb, 65536);
    cvt_bf16<<<256, 256, 0, stream>>>(wk, wkb, 65536);
    cvt_bf16<<<256, 256, 0, stream>>>(wv, wvb, 65536);
    cvt_bf16<<<256, 256, 0, stream>>>(wp, wpb, 65536);

    // GroupNorm
    gn_stats<<<512, 256, 0, stream>>>(x, stats);
    gn_apply_t<<<dim3(32, 16, 16), 256, 0, stream>>>(x, stats, gamma, beta, xnT);

    // qT[i][o] = sum_c xnT[i][c] Wq[o][c] + bq[o]   (M=1024, N=512, K=512)
    gemm_nt<2, 0, 0, bf16><<<dim3(4, 8, 16), 256, 0, stream>>>(
        xnT, BS, wqb, 0, qT, BS, bq, nullptr, 0, 512, 512, 1.f);
    gemm_nt<2, 0, 0, bf16><<<dim3(4, 8, 16), 256, 0, stream>>>(
        xnT, BS, wkb, 0, kT, BS, bk, nullptr, 0, 512, 512, 1.f);
    // v[o][j] = sum_c Wv[o][c] xnT[j][c] + bv[o]    (M=512, N=1024, K=512)
    gemm_nt<1, 0, 0, bf16><<<dim3(8, 4, 16), 256, 0, stream>>>(
        wvb, 0, xnT, BS, vv, BS, bv, nullptr, 0, 1024, 512, 1.f);

    const float scale = 0.044194173824159216f; // 512^-0.5
    for (int b0 = 0; b0 < 16; b0 += CB) {
        // E[i][j] = scale * sum_c qT[i][c] kT[j][c]  (M=N=1024, K=512)
        gemm_nt<0, 1, 0, float><<<dim3(8, 8, CB), 256, 0, stream>>>(
            qT + (size_t)b0 * BS, BS, kT + (size_t)b0 * BS, BS,
            E, ES, nullptr, nullptr, 0, 1024, 512, scale);
        softmax_row<<<CB * 1024, 256, 0, stream>>>(E, P);
        // O2[i][c] = sum_j P[i][j] v[c][j]           (M=1024, N=512, K=1024)
        gemm_nt<0, 0, 0, bf16><<<dim3(4, 8, CB), 256, 0, stream>>>(
            P, ES, vv + (size_t)b0 * BS, BS,
            O2 + (size_t)b0 * BS, BS, nullptr, nullptr, 0, 512, 1024, 1.f);
    }

    // out[o][i] = sum_c wp[o][c] O2[i][c] + bp[o] + x[o][i]  (M=512, N=1024, K=512)
    gemm_nt<1, 0, 1, float><<<dim3(8, 4, 16), 256, 0, stream>>>(
        wpb, 0, O2, BS, out, BS, bp, x, BS, 1024, 512, 1.f);
}

// Round 2
// 317.558 us; speedup vs baseline: 1.0279x; 1.0279x over previous
//
#include <hip/hip_runtime.h>
#include <hip/hip_bf16.h>

using bf16 = __hip_bfloat16;

typedef __attribute__((ext_vector_type(8))) __bf16 bf16x8;
typedef __attribute__((ext_vector_type(4))) float floatx4;

#define EPS 1e-6f

// ---------------------------------------------------------------------------
// async global->LDS, 16B per lane
// ---------------------------------------------------------------------------
__device__ __forceinline__ void load_lds16(const void* g, void* l) {
    __builtin_amdgcn_global_load_lds(
        (const __attribute__((address_space(1))) void*)g,
        (__attribute__((address_space(3))) void*)l, 16, 0, 0);
}

__device__ __forceinline__ void storeOut(float* p, float v) { *p = v; }
__device__ __forceinline__ void storeOut(bf16* p, float v) { *p = __float2bfloat16(v); }

// ---------------------------------------------------------------------------
// Canonical NT GEMM: D[m][n] = sum_k A[m][k] * B[n][k]
// A: rows m, row-stride lda. B: rows n, row-stride ldb. Both bf16, k-major.
// BM=BN=128, BK=32. 256 threads = 4 waves 2x2, wave = 64x64 (4x4 MFMA 16x16x32).
// BIAS_MODE: 0 none, 1 along m, 2 along n.
// SCALE_EN: v *= scale (before EXP).
// EXP_MODE: v = exp(v); accumulate row sums into rowsum[z*rsStride+row] (atomic).
// ROWDIV:   v *= 1/rowsum[z*rsStride+row].
// RESID_EN: v += resid[z*rStride + m*ldr + n] (fp32).
// ---------------------------------------------------------------------------
template <int BIAS_MODE, int SCALE_EN, int RESID_EN, int EXP_MODE, int ROWDIV,
          typename OutT>
__global__ __launch_bounds__(256) void gemm_nt(
    const bf16* __restrict__ A, long long aStride, int lda,
    const bf16* __restrict__ B, long long bStride, int ldb,
    OutT* __restrict__ D, long long dStride, int ldd,
    const float* __restrict__ bias,
    const float* __restrict__ resid, long long rStride, int ldr,
    float* __restrict__ rowsum, int rsStride,
    int K, float scale)
{
    __shared__ bf16 As[128 * 32];
    __shared__ bf16 Bs[128 * 32];

    const int tid  = threadIdx.x;
    const int lane = tid & 63;
    const int wave = tid >> 6;
    const int wm   = wave >> 1;      // 0..1
    const int wn   = wave & 1;       // 0..1
    const int m0   = blockIdx.y * 128;
    const int n0   = blockIdx.x * 128;
    const int z    = blockIdx.z;

    const bf16* Ab = A + (size_t)z * aStride + (size_t)m0 * lda;
    const bf16* Bb = B + (size_t)z * bStride + (size_t)n0 * ldb;

    floatx4 acc[4][4];
#pragma unroll
    for (int i = 0; i < 4; ++i)
#pragma unroll
        for (int j = 0; j < 4; ++j) acc[i][j] = (floatx4){0.f, 0.f, 0.f, 0.f};

    // LDS: 16B slot idx = kq*128 + row (kq = k-chunk of 8 bf16)
    const int fragBase = ((lane >> 4) * 128 + (lane & 15)) * 16;
    const char* AsB = (const char*)As;
    const char* BsB = (const char*)Bs;

    const int i1 = tid, i2 = tid + 256;
    const int r1 = i1 & 127, q1 = i1 >> 7;
    const int r2 = i2 & 127, q2 = i2 >> 7;

    const int kIters = K >> 5;
    for (int kt = 0; kt < kIters; ++kt) {
        const int k0 = kt << 5;
        load_lds16(Ab + (size_t)r1 * lda + k0 + q1 * 8, (char*)As + i1 * 16);
        load_lds16(Ab + (size_t)r2 * lda + k0 + q2 * 8, (char*)As + i2 * 16);
        load_lds16(Bb + (size_t)r1 * ldb + k0 + q1 * 8, (char*)Bs + i1 * 16);
        load_lds16(Bb + (size_t)r2 * ldb + k0 + q2 * 8, (char*)Bs + i2 * 16);
        __syncthreads();

        bf16x8 af[4], bfr[4];
#pragma unroll
        for (int im = 0; im < 4; ++im)
            af[im] = *(const bf16x8*)(AsB + fragBase + (wm * 64 + im * 16) * 16);
#pragma unroll
        for (int in = 0; in < 4; ++in)
            bfr[in] = *(const bf16x8*)(BsB + fragBase + (wn * 64 + in * 16) * 16);
#pragma unroll
        for (int im = 0; im < 4; ++im)
#pragma unroll
            for (int in = 0; in < 4; ++in)
                acc[im][in] = __builtin_amdgcn_mfma_f32_16x16x32_bf16(
                    af[im], bfr[in], acc[im][in], 0, 0, 0);
        __syncthreads();
    }

    // Epilogue. D frag layout: col = lane&15, row = (lane>>4)*4 + reg
    const size_t dbase = (size_t)z * dStride;
#pragma unroll
    for (int im = 0; im < 4; ++im) {
        const int gmb = m0 + wm * 64 + im * 16 + ((lane >> 4) << 2);
        float ri[4];
        if (ROWDIV) {
#pragma unroll
            for (int r = 0; r < 4; ++r)
                ri[r] = 1.f / rowsum[(size_t)z * rsStride + gmb + r];
        }
        float rsum[4] = {0.f, 0.f, 0.f, 0.f};
#pragma unroll
        for (int in = 0; in < 4; ++in) {
            const int gn = n0 + wn * 64 + in * 16 + (lane & 15);
            float bn = 0.f;
            if (BIAS_MODE == 2) bn = bias[gn];
#pragma unroll
            for (int r = 0; r < 4; ++r) {
                const int gm = gmb + r;
                float v = acc[im][in][r];
                if (SCALE_EN) v *= scale;
                if (EXP_MODE) { v = __expf(v); rsum[r] += v; }
                if (ROWDIV) v *= ri[r];
                if (BIAS_MODE == 1) v += bias[gm];
                if (BIAS_MODE == 2) v += bn;
                if (RESID_EN)
                    v += resid[(size_t)z * rStride + (size_t)gm * ldr + gn];
                storeOut(D + dbase + (size_t)gm * ldd + gn, v);
            }
        }
        if (EXP_MODE) {
#pragma unroll
            for (int r = 0; r < 4; ++r) {
                float s = rsum[r];
                s += __shfl_xor(s, 1);
                s += __shfl_xor(s, 2);
                s += __shfl_xor(s, 4);
                s += __shfl_xor(s, 8);
                if ((lane & 15) == 0)
                    atomicAdd(rowsum + (size_t)z * rsStride + gmb + r, s);
            }
        }
    }
}

// ---------------------------------------------------------------------------
// GroupNorm stats: one block per (b, g); 16 ch x 1024 = 16384 contiguous floats
// ---------------------------------------------------------------------------
__global__ __launch_bounds__(256) void gn_stats(const float* __restrict__ x,
                                                float* __restrict__ stats)
{
    const int bg = blockIdx.x;
    const float4* p = (const float4*)(x + (size_t)bg * 16384);
    float s = 0.f, ss = 0.f;
    for (int i = threadIdx.x; i < 4096; i += 256) {
        float4 v = p[i];
        s  += v.x + v.y + v.z + v.w;
        ss += v.x * v.x + v.y * v.y + v.z * v.z + v.w * v.w;
    }
#pragma unroll
    for (int off = 32; off; off >>= 1) {
        s  += __shfl_down(s, off);
        ss += __shfl_down(ss, off);
    }
    __shared__ float rs[4], rss[4];
    const int wv = threadIdx.x >> 6;
    if ((threadIdx.x & 63) == 0) { rs[wv] = s; rss[wv] = ss; }
    __syncthreads();
    if (threadIdx.x == 0) {
        float S  = rs[0] + rs[1] + rs[2] + rs[3];
        float SS = rss[0] + rss[1] + rss[2] + rss[3];
        float mean = S * (1.f / 16384.f);
        float var  = SS * (1.f / 16384.f) - mean * mean;
        stats[2 * bg]     = mean;
        stats[2 * bg + 1] = rsqrtf(var + EPS);
    }
}

// ---------------------------------------------------------------------------
// GN apply + transpose: x (B,512,1024) fp32 -> xnT (B,1024,512) bf16
// ---------------------------------------------------------------------------
__global__ __launch_bounds__(256) void gn_apply_t(const float* __restrict__ x,
                                                  const float* __restrict__ stats,
                                                  const float* __restrict__ gamma,
                                                  const float* __restrict__ beta,
                                                  bf16* __restrict__ xnT)
{
    __shared__ bf16 tile[32][36];
    const int b = blockIdx.z, c0 = blockIdx.y * 32, i0 = blockIdx.x * 32;
    {
        const int cc = threadIdx.x >> 3;
        const int i4 = (threadIdx.x & 7) << 2;
        const int c  = c0 + cc;
        const float mean = stats[2 * ((b << 5) + (c >> 4))];
        const float rstd = stats[2 * ((b << 5) + (c >> 4)) + 1];
        const float a  = gamma[c] * rstd;
        const float bb = beta[c] - mean * a;
        float4 v = *(const float4*)(x + (((size_t)(b * 512 + c)) << 10) + i0 + i4);
        tile[cc][i4 + 0] = __float2bfloat16(v.x * a + bb);
        tile[cc][i4 + 1] = __float2bfloat16(v.y * a + bb);
        tile[cc][i4 + 2] = __float2bfloat16(v.z * a + bb);
        tile[cc][i4 + 3] = __float2bfloat16(v.w * a + bb);
    }
    __syncthreads();
    {
        const int ii = threadIdx.x >> 3;
        const int c4 = (threadIdx.x & 7) << 2;
        union { bf16 h[4]; uint2 u; } pk;
        pk.h[0] = tile[c4 + 0][ii];
        pk.h[1] = tile[c4 + 1][ii];
        pk.h[2] = tile[c4 + 2][ii];
        pk.h[3] = tile[c4 + 3][ii];
        *((uint2*)(xnT + (((size_t)(b * 1024 + i0 + ii)) << 9) + c0 + c4)) = pk.u;
    }
}

// ---------------------------------------------------------------------------
// fp32 -> bf16 convert (n4 float4 groups)
// ---------------------------------------------------------------------------
__global__ __launch_bounds__(256) void cvt_bf16(const float* __restrict__ s,
                                                bf16* __restrict__ d, int n4)
{
    const int i = blockIdx.x * 256 + threadIdx.x;
    if (i < n4) {
        float4 v = ((const float4*)s)[i];
        union { bf16 h[4]; uint2 u; } pk;
        pk.h[0] = __float2bfloat16(v.x);
        pk.h[1] = __float2bfloat16(v.y);
        pk.h[2] = __float2bfloat16(v.z);
        pk.h[3] = __float2bfloat16(v.w);
        ((uint2*)d)[i] = pk.u;
    }
}

// ---------------------------------------------------------------------------
extern "C" void kernel_launch(void* const* d_in, const int* in_sizes, int n_in,
                              void* d_out, int out_size, void* d_ws, size_t ws_size,
                              hipStream_t stream)
{
    const float* x     = (const float*)d_in[0];
    const float* gamma = (const float*)d_in[1];
    const float* beta  = (const float*)d_in[2];
    const float* wq    = (const float*)d_in[3];
    const float* bq    = (const float*)d_in[4];
    const float* wk    = (const float*)d_in[5];
    const float* bk    = (const float*)d_in[6];
    const float* wv    = (const float*)d_in[7];
    const float* bv    = (const float*)d_in[8];
    const float* wp    = (const float*)d_in[9];
    const float* bp    = (const float*)d_in[10];
    float* out = (float*)d_out;

    char* ws = (char*)d_ws;
    size_t off = 0;
    auto alloc = [&](size_t bytes) -> char* {
        char* p = ws + off;
        off += (bytes + 255) & ~(size_t)255;
        return p;
    };

    const long long S  = 1024, C = 512;
    const long long BS = S * C;           // elements per batch of x/q/v/...
    const long long ES = S * S;           // elements per batch of P/qkT

    float* stats = (float*)alloc(512 * 2 * sizeof(float));
    float* bqk   = (float*)alloc(1024 * sizeof(float));
    float* rowsum = (float*)alloc((size_t)16 * S * sizeof(float));
    bf16* wqkb = (bf16*)alloc((size_t)2 * C * C * 2);   // [wq; wk] rows
    bf16* wvb  = (bf16*)alloc((size_t)C * C * 2);
    bf16* wpb  = (bf16*)alloc((size_t)C * C * 2);
    bf16* xnT  = (bf16*)alloc((size_t)16 * BS * 2);
    bf16* qkT  = (bf16*)alloc((size_t)16 * ES * 2);     // (B,1024,1024): [qT|kT]
    bf16* vv   = (bf16*)alloc((size_t)16 * BS * 2);
    bf16* O2   = (bf16*)alloc((size_t)16 * BS * 2);

    // P (bf16) chunked by batch if workspace tight
    int CB = 16;
    while (CB > 1 && off + (size_t)CB * ES * 2 + 1024 > ws_size) CB >>= 1;
    bf16* P = (bf16*)alloc((size_t)CB * ES * 2);

    // weights fp32 -> bf16 ([wq;wk] concatenated), biases concat
    cvt_bf16<<<256, 256, 0, stream>>>(wq, wqkb, 65536);
    cvt_bf16<<<256, 256, 0, stream>>>(wk, wqkb + (size_t)C * C, 65536);
    cvt_bf16<<<256, 256, 0, stream>>>(wv, wvb, 65536);
    cvt_bf16<<<256, 256, 0, stream>>>(wp, wpb, 65536);
    hipMemcpyAsync(bqk, bq, 512 * sizeof(float), hipMemcpyDeviceToDevice, stream);
    hipMemcpyAsync(bqk + 512, bk, 512 * sizeof(float), hipMemcpyDeviceToDevice, stream);
    hipMemsetAsync(rowsum, 0, (size_t)16 * S * sizeof(float), stream);

    // GroupNorm
    gn_stats<<<512, 256, 0, stream>>>(x, stats);
    gn_apply_t<<<dim3(32, 16, 16), 256, 0, stream>>>(x, stats, gamma, beta, xnT);

    // qkT[i][o] = sum_c xnT[i][c] Wqk[o][c] + bqk[o]  (M=1024, N=1024, K=512)
    gemm_nt<2, 0, 0, 0, 0, bf16><<<dim3(8, 8, 16), 256, 0, stream>>>(
        xnT, BS, 512, wqkb, 0, 512, qkT, ES, 1024,
        bqk, nullptr, 0, 0, nullptr, 0, 512, 1.f);
    // v[o][j] = sum_c Wv[o][c] xnT[j][c] + bv[o]      (M=512, N=1024, K=512)
    gemm_nt<1, 0, 0, 0, 0, bf16><<<dim3(8, 4, 16), 256, 0, stream>>>(
        wvb, 0, 512, xnT, BS, 512, vv, BS, 1024,
        bv, nullptr, 0, 0, nullptr, 0, 512, 1.f);

    const float scale = 0.044194173824159216f; // 512^-0.5
    for (int b0 = 0; b0 < 16; b0 += CB) {
        // P[i][j] = exp(scale * sum_c qT[i][c] kT[j][c]); rowsum[i] += ...
        gemm_nt<0, 1, 0, 1, 0, bf16><<<dim3(8, 8, CB), 256, 0, stream>>>(
            qkT + (size_t)b0 * ES, ES, 1024,
            qkT + (size_t)b0 * ES + 512, ES, 1024,
            P, ES, 1024,
            nullptr, nullptr, 0, 0, rowsum + (size_t)b0 * S, (int)S,
            512, scale);
        // O2[i][c] = (sum_j P[i][j] v[c][j]) / rowsum[i]  (M=1024,N=512,K=1024)
        gemm_nt<0, 0, 0, 0, 1, bf16><<<dim3(4, 8, CB), 256, 0, stream>>>(
            P, ES, 1024,
            vv + (size_t)b0 * BS, BS, 1024,
            O2 + (size_t)b0 * BS, BS, 512,
            nullptr, nullptr, 0, 0, rowsum + (size_t)b0 * S, (int)S,
            1024, 1.f);
    }

    // out[o][i] = sum_c wp[o][c] O2[i][c] + bp[o] + x[o][i]  (M=512,N=1024,K=512)
    gemm_nt<1, 0, 1, 0, 0, float><<<dim3(8, 4, 16), 256, 0, stream>>>(
        wpb, 0, 512, O2, BS, 512, out, BS, 1024,
        bp, x, BS, 1024, nullptr, 0, 512, 1.f);
}